// Round 10
// baseline (30.995 us; speedup 1.0000x reference)
//
#include <hip/hip_runtime.h>
#include <math.h>

#define BLK 512          // threads per block (8 waves)
#define GSZ 8            // checkpoints (m values) per block
#define TILE 2048        // k-elements per LDS tile (= BLK*4)
#define NW (BLK / 64)    // waves per block

#if __has_builtin(__builtin_amdgcn_rsqf)
#define RSQF(x) __builtin_amdgcn_rsqf(x)
#else
#define RSQF(x) (1.0f / sqrtf(x))
#endif

// fast x^e for x>0 via hw exp2/log2 (~1e-6 rel err, vs 0.176 abs budget)
__device__ __forceinline__ float fast_pow(float x, float e) {
  return __expf(e * __logf(x));
}

// ---------------------------------------------------------------------------
// Direct global->LDS async copy, 16B per lane (global_load_lds_dwordx4).
// LDS dest is wave-uniform base + lane*16 (HW rule); global src is per-lane.
// ---------------------------------------------------------------------------
#if __has_builtin(__builtin_amdgcn_global_load_lds)
__device__ __forceinline__ void gl_lds16(const float* g, float* l) {
  __builtin_amdgcn_global_load_lds(
      (const __attribute__((address_space(1))) uint32_t*)g,
      (__attribute__((address_space(3))) uint32_t*)l, 16, 0, 0);
}
#define STAGE_ONE(src, gi, dst, lb) gl_lds16((src) + (gi), &(dst)[lb])
#else
#define STAGE_ONE(src, gi, dst, lb) /* fallback: reg-staged copy */ \
  *(float4*)&(dst)[(gi) & (TILE - 1)] = *(const float4*)((src) + (gi))
#endif

// ---------------------------------------------------------------------------
// Precompute (Tpad elements, Tpad = multiple of TILE):
//   cpw[k] = C * lrs[k]^(-gamma)          (1 <= k < T)
//   dd[k]  = 1 - cpw[k]*lr_sum[k-1]       so inner = fma(cpw, Ssum, dd)
//   gapp[k] = lr_gap[k]
//   k==0 and k>=T: cpw=0, dd=1, gapp=0 -> term contributes 0
// ---------------------------------------------------------------------------
__global__ __launch_bounds__(256) void precompute_kernel(
    const float* __restrict__ lrs, const float* __restrict__ lr_sum,
    const float* __restrict__ lr_gap,
    float* __restrict__ cpw, float* __restrict__ dd, float* __restrict__ gapp,
    const float* __restrict__ gamma_p, const float* __restrict__ C_p,
    int T, int Tpad) {
  int i = blockIdx.x * 256 + threadIdx.x;
  if (i >= Tpad) return;
  if (i == 0 || i >= T) {
    cpw[i] = 0.0f; dd[i] = 1.0f; gapp[i] = 0.0f;
    return;
  }
  float c = C_p[0] * fast_pow(lrs[i], -gamma_p[0]);
  cpw[i]  = c;
  dd[i]   = fmaf(-c, lr_sum[i - 1], 1.0f);
  gapp[i] = lr_gap[i];
}

// ---------------------------------------------------------------------------
// Per-tile compute: thread handles tile elements [tid*4, tid*4+4) from LDS.
// MASKED variant selects on p AFTER the transcendental (0*NaN poison,
// round-2 bug): masked-out k can have inner <= 0.
// ---------------------------------------------------------------------------
template <bool USE_RSQ, bool MASKED>
__device__ __forceinline__ void tile_terms(
    const float (&buf)[3][TILE], int tid, int kglob,
    const float (&Ss)[GSZ], const int (&sv)[GSZ], float (&acc)[GSZ],
    float nb) {
  float4 c4 = *(const float4*)&buf[0][tid * 4];
  float4 d4 = *(const float4*)&buf[1][tid * 4];
  float4 g4 = *(const float4*)&buf[2][tid * 4];
  const float ce[4] = {c4.x, c4.y, c4.z, c4.w};
  const float de[4] = {d4.x, d4.y, d4.z, d4.w};
  const float ge[4] = {g4.x, g4.y, g4.z, g4.w};
#pragma unroll
  for (int e = 0; e < 4; ++e) {
#pragma unroll
    for (int j = 0; j < GSZ; ++j) {
      float inner = fmaf(ce[e], Ss[j], de[e]);
      float p = USE_RSQ ? RSQF(inner) : __expf(nb * __logf(inner));
      float pm = (!MASKED || (kglob + e <= sv[j])) ? p : 0.0f;
      acc[j] = fmaf(ge[e], pm, acc[j]);
    }
  }
}

// ---------------------------------------------------------------------------
// Main: ONE chunk (GSZ checkpoints) per block; k-range walked in TILE-sized
// LDS tiles, double-buffered, staged via global_load_lds (width 16).
// Loop shape (T3 minimum 2-phase): stage(next) -> compute(cur) -> barrier.
// The barrier's vmcnt(0) drain is the staging completion wait; staging of
// tile t+1 overlaps compute of tile t. LDS 48.25 KB -> 3 blocks/CU.
// ---------------------------------------------------------------------------
template <bool USE_RSQ>
__device__ __forceinline__ void ld_loop(
    const float* __restrict__ cpw, const float* __restrict__ dd,
    const float* __restrict__ gapp, float (&lbuf)[2][3][TILE],
    const float (&Ss)[GSZ], const int (&sv)[GSZ], float (&acc)[GSZ],
    int nfull, int ntile, float nb, int tid) {
  int lb = (tid & ~63) * 4;  // wave-uniform LDS base (floats)

  // prologue: stage tile 0
  STAGE_ONE(cpw,  tid * 4, lbuf[0][0], lb);
  STAGE_ONE(dd,   tid * 4, lbuf[0][1], lb);
  STAGE_ONE(gapp, tid * 4, lbuf[0][2], lb);
  __syncthreads();

  for (int t = 0; t < ntile; ++t) {
    int cur = t & 1;
    if (t + 1 < ntile) {  // block-uniform branch
      int gi = (t + 1) * TILE + tid * 4;
      STAGE_ONE(cpw,  gi, lbuf[cur ^ 1][0], lb);
      STAGE_ONE(dd,   gi, lbuf[cur ^ 1][1], lb);
      STAGE_ONE(gapp, gi, lbuf[cur ^ 1][2], lb);
    }
    int kglob = t * TILE + tid * 4;
    if (t < nfull)  // block-uniform
      tile_terms<USE_RSQ, false>(lbuf[cur], tid, kglob, Ss, sv, acc, nb);
    else
      tile_terms<USE_RSQ, true>(lbuf[cur], tid, kglob, Ss, sv, acc, nb);
    __syncthreads();  // staged next-tile complete; everyone done with cur
  }
}

__global__ __launch_bounds__(BLK, 8) void ld_kernel(
    const float* __restrict__ S1, const int* __restrict__ step,
    const float* __restrict__ loss, const float* __restrict__ lrs,
    const float* __restrict__ cpw, const float* __restrict__ dd,
    const float* __restrict__ gapp,
    const float* __restrict__ L0_p, const float* __restrict__ A_p,
    const float* __restrict__ alpha_p, const float* __restrict__ B_p,
    const float* __restrict__ beta_p,
    float* __restrict__ hub) {
  __shared__ float lbuf[2][3][TILE];
  __shared__ float wacc[NW][GSZ];

  int tid = threadIdx.x;
  int mbase = blockIdx.x * GSZ;

  float Ss[GSZ]; int sv[GSZ]; float acc[GSZ];
#pragma unroll
  for (int j = 0; j < GSZ; ++j) {
    Ss[j] = S1[mbase + j];
    sv[j] = step[mbase + j];
    acc[j] = 0.0f;
  }
  int smin = sv[0], smax = sv[0];
#pragma unroll
  for (int j = 1; j < GSZ; ++j) {
    smin = min(smin, sv[j]);
    smax = max(smax, sv[j]);
  }
  int nfull = (smin + 1) / TILE;  // tiles fully unmasked
  int ntile = smax / TILE + 1;    // tiles needed

  float beta = beta_p[0];
  float nb = -beta;

  if (beta == 0.5f)
    ld_loop<true>(cpw, dd, gapp, lbuf, Ss, sv, acc, nfull, ntile, nb, tid);
  else
    ld_loop<false>(cpw, dd, gapp, lbuf, Ss, sv, acc, nfull, ntile, nb, tid);

  // block reduction: 64-lane shuffle, then across the 8 waves via LDS
  int lane = tid & 63, wid = tid >> 6;
#pragma unroll
  for (int j = 0; j < GSZ; ++j) {
    float v = acc[j];
#pragma unroll
    for (int off = 32; off; off >>= 1) v += __shfl_down(v, off, 64);
    if (lane == 0) wacc[wid][j] = v;
  }
  __syncthreads();

  if (tid < GSZ) {
    int j = tid;
    int m = mbase + j;
    float sgp = 0.0f;
#pragma unroll
    for (int w = 0; w < NW; ++w) sgp += wacc[w][j];
    int s = step[m];
    float Ssum = S1[m];
    float LD = (lrs[0] - lrs[s]) - sgp;   // telescoped gap sum
    float pred = L0_p[0] + A_p[0] * fast_pow(Ssum, -alpha_p[0]) + B_p[0] * LD;
    pred = fmaxf(pred, 1e-10f);
    float r = __logf(loss[m]) - __logf(pred);
    float a = fabsf(r);
    const float dlt = 0.001f;
    hub[m] = (a <= dlt) ? (0.5f * r * r) : (dlt * (a - 0.5f * dlt));
  }
}

// ---------------------------------------------------------------------------
// Deterministic single-block reduction of hub[0..M) -> out[0]
// ---------------------------------------------------------------------------
__global__ __launch_bounds__(1024) void reduce_kernel(
    const float* __restrict__ hub, float* __restrict__ out, int M) {
  float acc = 0.0f;
  for (int i = threadIdx.x; i < M; i += 1024) acc += hub[i];
#pragma unroll
  for (int off = 32; off; off >>= 1) acc += __shfl_down(acc, off, 64);
  __shared__ float wacc[16];
  int lane = threadIdx.x & 63, wid = threadIdx.x >> 6;
  if (lane == 0) wacc[wid] = acc;
  __syncthreads();
  if (threadIdx.x == 0) {
    float t = 0.0f;
#pragma unroll
    for (int i = 0; i < 16; ++i) t += wacc[i];
    out[0] = t;
  }
}

extern "C" void kernel_launch(void* const* d_in, const int* in_sizes, int n_in,
                              void* d_out, int out_size, void* d_ws, size_t ws_size,
                              hipStream_t stream) {
  const float* S1      = (const float*)d_in[0];
  const float* lrs     = (const float*)d_in[1];
  const float* lr_sum  = (const float*)d_in[2];
  const int*   step    = (const int*)  d_in[3];
  const float* lr_gap  = (const float*)d_in[4];
  const float* loss    = (const float*)d_in[5];
  const float* L0_p    = (const float*)d_in[6];
  const float* A_p     = (const float*)d_in[7];
  const float* alpha_p = (const float*)d_in[8];
  const float* B_p     = (const float*)d_in[9];
  const float* C_p     = (const float*)d_in[10];
  const float* beta_p  = (const float*)d_in[11];
  const float* gamma_p = (const float*)d_in[12];

  int M = in_sizes[0];
  int T = in_sizes[1];
  int Tpad = ((T + TILE - 1) / TILE) * TILE;  // staging never over-runs

  float* cpw  = (float*)d_ws;   // Tpad floats
  float* dd   = cpw + Tpad;     // Tpad floats
  float* gapp = dd + Tpad;      // Tpad floats
  float* hub  = gapp + Tpad;    // M floats

  int nchunk = M / GSZ;         // 1024 blocks, one chunk each

  precompute_kernel<<<(Tpad + 255) / 256, 256, 0, stream>>>(
      lrs, lr_sum, lr_gap, cpw, dd, gapp, gamma_p, C_p, T, Tpad);
  ld_kernel<<<nchunk, BLK, 0, stream>>>(
      S1, step, loss, lrs, cpw, dd, gapp,
      L0_p, A_p, alpha_p, B_p, beta_p, hub);
  reduce_kernel<<<1, 1024, 0, stream>>>(hub, (float*)d_out, M);
}

// Round 11
// 26.417 us; speedup vs baseline: 1.1733x; 1.1733x over previous
//
#include <hip/hip_runtime.h>
#include <math.h>

#define BLK 512          // threads per block (8 waves)
#define GSZ 8            // checkpoints (m values) per block
#define SEGW 128         // k-elements per moment segment
#define NSEG_NEAR 6      // segments before s computed exactly
#define NDEG 8           // expansion degree (moments 0..NDEG)
#define SEGSTRIDE 16     // floats per segment record: d0, M'[0..8], pad

#if __has_builtin(__builtin_amdgcn_rsqf)
#define RSQF(x) __builtin_amdgcn_rsqf(x)
#else
#define RSQF(x) (1.0f / sqrtf(x))
#endif
#if __has_builtin(__builtin_amdgcn_rcpf)
#define RCPF(x) __builtin_amdgcn_rcpf(x)
#else
#define RCPF(x) (1.0f / (x))
#endif

// fast x^e for x>0 via hw exp2/log2 (~1e-6 rel err, vs 0.176 abs budget)
__device__ __forceinline__ float fast_pow(float x, float e) {
  return __expf(e * __logf(x));
}

// ---------------------------------------------------------------------------
// Kernel A — per-k precompute (Tpad elements):
//   cpw[k]=c=C*lrs^-g;  dd[k]=1-c*L[k-1]  (near path: inner=fma(c,S,dd))
//   gapp[k]=lr_gap[k];  dk[k]=1/c-L[k-1]; wk[k]=g*c^-beta  (far path)
//   k==0 or k>=T: zero contribution (w=0,g=0), benign values elsewhere.
// ---------------------------------------------------------------------------
__global__ __launch_bounds__(256) void precompute_kernel(
    const float* __restrict__ lrs, const float* __restrict__ lr_sum,
    const float* __restrict__ lr_gap,
    float* __restrict__ cpw, float* __restrict__ dd, float* __restrict__ gapp,
    float* __restrict__ dk, float* __restrict__ wk,
    const float* __restrict__ gamma_p, const float* __restrict__ C_p,
    const float* __restrict__ beta_p, int T, int Tpad) {
  int i = blockIdx.x * 256 + threadIdx.x;
  if (i >= Tpad) return;
  if (i == 0 || i >= T) {
    cpw[i] = 0.0f; dd[i] = 1.0f; gapp[i] = 0.0f; dk[i] = 0.0f; wk[i] = 0.0f;
    return;
  }
  float g = lr_gap[i];
  float L = lr_sum[i - 1];
  float c = C_p[0] * fast_pow(lrs[i], -gamma_p[0]);
  cpw[i]  = c;
  dd[i]   = fmaf(-c, L, 1.0f);
  gapp[i] = g;
  dk[i]   = 1.0f / c - L;               // precise div ok in precompute
  wk[i]   = g * fast_pow(c, -beta_p[0]);
}

// ---------------------------------------------------------------------------
// Kernel B — per-segment moments: d0 = mean(dk), M'[n] = b_n * sum wk*(dk-d0)^n
// (b_n = binom(-beta,n) premultiplied). One 128-thread block per segment.
// Deterministic fixed-order shuffle reductions.
// ---------------------------------------------------------------------------
__global__ __launch_bounds__(128) void moments_kernel(
    const float* __restrict__ dk, const float* __restrict__ wk,
    float* __restrict__ segdata, const float* __restrict__ beta_p) {
  int seg = blockIdx.x, t = threadIdx.x;
  int k = seg * SEGW + t;
  float d = dk[k], w = wk[k];
  __shared__ float sh[2];

  float v = d;
#pragma unroll
  for (int off = 32; off; off >>= 1) v += __shfl_down(v, off, 64);
  if ((t & 63) == 0) sh[t >> 6] = v;
  __syncthreads();
  float d0 = (sh[0] + sh[1]) * (1.0f / 128.0f);
  __syncthreads();

  float delta = d - d0;
  float p = w;
  float beta = beta_p[0];
  float b = 1.0f;
  for (int n = 0; n <= NDEG; ++n) {
    v = p;
#pragma unroll
    for (int off = 32; off; off >>= 1) v += __shfl_down(v, off, 64);
    if ((t & 63) == 0) sh[t >> 6] = v;
    __syncthreads();
    if (t == 0) segdata[seg * SEGSTRIDE + 1 + n] = b * (sh[0] + sh[1]);
    __syncthreads();
    p *= delta;
    b *= (-beta - (float)n) / (float)(n + 1);
  }
  if (t == 0) segdata[seg * SEGSTRIDE] = d0;
}

// ---------------------------------------------------------------------------
// Kernel C — main. Per block: GSZ checkpoints.
// FAR: thread t handles segment t (<128 segs total): contrib_j =
//   t_j * Horner_r(M'), masked select-on-VALUE (NaN-safe, round-2 rule).
// NEAR: masked exact sweeps over k in [base, smax] (usually ONE sweep).
// ---------------------------------------------------------------------------
template <bool USE_RSQ>
__device__ __forceinline__ void body(
    const float* __restrict__ cpw, const float* __restrict__ dd,
    const float* __restrict__ gapp, const float* __restrict__ segdata,
    const float (&Ss)[GSZ], const int (&sv)[GSZ], const int (&kseg)[GSZ],
    float (&acc)[GSZ], int nsegmax, int base, int smaxb, float nb, int tid) {
  // ---- far: moment segments ----
  for (int seg = tid; seg < nsegmax; seg += BLK) {
    const float* sd = segdata + seg * SEGSTRIDE;
    float d0 = sd[0];
    float m[NDEG + 1];
#pragma unroll
    for (int n = 0; n <= NDEG; ++n) m[n] = sd[1 + n];
#pragma unroll
    for (int j = 0; j < GSZ; ++j) {
      float s_ = Ss[j] + d0;                 // may be <=0 if masked out
      float r = RCPF(s_);
      float tb = USE_RSQ ? RSQF(s_) : fast_pow(s_, nb);
      float h = m[NDEG];
#pragma unroll
      for (int n = NDEG - 1; n >= 0; --n) h = fmaf(h, r, m[n]);
      float contrib = tb * h;
      acc[j] += (seg < kseg[j]) ? contrib : 0.0f;  // select AFTER compute
    }
  }

  // ---- near: exact masked sweeps ----
  for (int kb = base + tid * 4; kb <= smaxb; kb += BLK * 4) {
    float4 c4 = *(const float4*)(cpw + kb);
    float4 d4 = *(const float4*)(dd + kb);
    float4 g4 = *(const float4*)(gapp + kb);
    const float ce[4] = {c4.x, c4.y, c4.z, c4.w};
    const float de[4] = {d4.x, d4.y, d4.z, d4.w};
    const float ge[4] = {g4.x, g4.y, g4.z, g4.w};
#pragma unroll
    for (int e = 0; e < 4; ++e) {
#pragma unroll
      for (int j = 0; j < GSZ; ++j) {
        float inner = fmaf(ce[e], Ss[j], de[e]);  // may be <=0 if masked
        float p = USE_RSQ ? RSQF(inner) : __expf(nb * __logf(inner));
        int kk = kb + e;
        float pm = (kk >= (kseg[j] << 7) && kk <= sv[j]) ? p : 0.0f;
        acc[j] = fmaf(ge[e], pm, acc[j]);
      }
    }
  }
}

__global__ __launch_bounds__(BLK, 4) void ld_kernel(
    const float* __restrict__ S1, const int* __restrict__ step,
    const float* __restrict__ loss, const float* __restrict__ lrs,
    const float* __restrict__ cpw, const float* __restrict__ dd,
    const float* __restrict__ gapp, const float* __restrict__ segdata,
    const float* __restrict__ L0_p, const float* __restrict__ A_p,
    const float* __restrict__ alpha_p, const float* __restrict__ B_p,
    const float* __restrict__ beta_p,
    float* __restrict__ hub) {
  __shared__ float wacc[BLK / 64][GSZ];
  int tid = threadIdx.x;
  int mbase = blockIdx.x * GSZ;

  float Ss[GSZ]; int sv[GSZ]; int kseg[GSZ]; float acc[GSZ];
#pragma unroll
  for (int j = 0; j < GSZ; ++j) {
    Ss[j] = S1[mbase + j];
    sv[j] = step[mbase + j];
    kseg[j] = max(0, (sv[j] >> 7) - NSEG_NEAR);
    acc[j] = 0.0f;
  }
  int ksegmin = kseg[0], nsegmax = kseg[0], smaxb = sv[0];
#pragma unroll
  for (int j = 1; j < GSZ; ++j) {
    ksegmin = min(ksegmin, kseg[j]);
    nsegmax = max(nsegmax, kseg[j]);
    smaxb = max(smaxb, sv[j]);
  }
  int base = ksegmin << 7;  // multiple of 128 -> 16B-aligned float4 reads

  float beta = beta_p[0];
  float nb = -beta;
  if (beta == 0.5f)
    body<true>(cpw, dd, gapp, segdata, Ss, sv, kseg, acc,
               nsegmax, base, smaxb, nb, tid);
  else
    body<false>(cpw, dd, gapp, segdata, Ss, sv, kseg, acc,
                nsegmax, base, smaxb, nb, tid);

  // block reduction: 64-lane shuffle, then across waves via LDS
  int lane = tid & 63, wid = tid >> 6;
#pragma unroll
  for (int j = 0; j < GSZ; ++j) {
    float v = acc[j];
#pragma unroll
    for (int off = 32; off; off >>= 1) v += __shfl_down(v, off, 64);
    if (lane == 0) wacc[wid][j] = v;
  }
  __syncthreads();

  if (tid < GSZ) {
    int j = tid;
    int m = mbase + j;
    float sgp = 0.0f;
#pragma unroll
    for (int w = 0; w < BLK / 64; ++w) sgp += wacc[w][j];
    int s = step[m];
    float Ssum = S1[m];
    float LD = (lrs[0] - lrs[s]) - sgp;   // telescoped gap sum
    float pred = L0_p[0] + A_p[0] * fast_pow(Ssum, -alpha_p[0]) + B_p[0] * LD;
    pred = fmaxf(pred, 1e-10f);
    float r = __logf(loss[m]) - __logf(pred);
    float a = fabsf(r);
    const float dlt = 0.001f;
    hub[m] = (a <= dlt) ? (0.5f * r * r) : (dlt * (a - 0.5f * dlt));
  }
}

// ---------------------------------------------------------------------------
// Deterministic single-block reduction of hub[0..M) -> out[0]
// ---------------------------------------------------------------------------
__global__ __launch_bounds__(1024) void reduce_kernel(
    const float* __restrict__ hub, float* __restrict__ out, int M) {
  float acc = 0.0f;
  for (int i = threadIdx.x; i < M; i += 1024) acc += hub[i];
#pragma unroll
  for (int off = 32; off; off >>= 1) acc += __shfl_down(acc, off, 64);
  __shared__ float wacc[16];
  int lane = threadIdx.x & 63, wid = threadIdx.x >> 6;
  if (lane == 0) wacc[wid] = acc;
  __syncthreads();
  if (threadIdx.x == 0) {
    float t = 0.0f;
#pragma unroll
    for (int i = 0; i < 16; ++i) t += wacc[i];
    out[0] = t;
  }
}

extern "C" void kernel_launch(void* const* d_in, const int* in_sizes, int n_in,
                              void* d_out, int out_size, void* d_ws, size_t ws_size,
                              hipStream_t stream) {
  const float* S1      = (const float*)d_in[0];
  const float* lrs     = (const float*)d_in[1];
  const float* lr_sum  = (const float*)d_in[2];
  const int*   step    = (const int*)  d_in[3];
  const float* lr_gap  = (const float*)d_in[4];
  const float* loss    = (const float*)d_in[5];
  const float* L0_p    = (const float*)d_in[6];
  const float* A_p     = (const float*)d_in[7];
  const float* alpha_p = (const float*)d_in[8];
  const float* B_p     = (const float*)d_in[9];
  const float* C_p     = (const float*)d_in[10];
  const float* beta_p  = (const float*)d_in[11];
  const float* gamma_p = (const float*)d_in[12];

  int M = in_sizes[0];
  int T = in_sizes[1];
  int Tpad = ((T + 2047) / 2048) * 2048;   // sweep/float4 overrun safety
  int nseg = Tpad / SEGW;

  float* cpw  = (float*)d_ws;      // Tpad
  float* dd   = cpw + Tpad;        // Tpad
  float* gapp = dd + Tpad;         // Tpad
  float* dk   = gapp + Tpad;       // Tpad
  float* wk   = dk + Tpad;         // Tpad
  float* segd = wk + Tpad;         // nseg * SEGSTRIDE
  float* hub  = segd + nseg * SEGSTRIDE;  // M

  precompute_kernel<<<(Tpad + 255) / 256, 256, 0, stream>>>(
      lrs, lr_sum, lr_gap, cpw, dd, gapp, dk, wk,
      gamma_p, C_p, beta_p, T, Tpad);
  moments_kernel<<<nseg, 128, 0, stream>>>(dk, wk, segd, beta_p);
  ld_kernel<<<M / GSZ, BLK, 0, stream>>>(
      S1, step, loss, lrs, cpw, dd, gapp, segd,
      L0_p, A_p, alpha_p, B_p, beta_p, hub);
  reduce_kernel<<<1, 1024, 0, stream>>>(hub, (float*)d_out, M);
}